// Round 4
// baseline (25712.958 us; speedup 1.0000x reference)
//
#include <hip/hip_runtime.h>
#include <cstdint>
#include <cstddef>

// ---------- small helpers ----------
typedef __bf16 bf16x8 __attribute__((ext_vector_type(8)));
typedef float  f32x4  __attribute__((ext_vector_type(4)));

__device__ __forceinline__ float b2f(unsigned short u) {
    union { uint32_t i; float f; } x; x.i = ((uint32_t)u) << 16; return x.f;
}
__device__ __forceinline__ unsigned short f2bf(float f) {
    uint32_t u = __float_as_uint(f);
    uint32_t r = (u + 0x7FFFu + ((u >> 16) & 1u)) >> 16;   // RNE, no NaN in data
    return (unsigned short)r;
}

// JAX threefry2x32 (20 rounds), usable host+device
__host__ __device__ inline void tf2x32(uint32_t k0, uint32_t k1,
                                       uint32_t x0, uint32_t x1,
                                       uint32_t& o0, uint32_t& o1) {
    uint32_t ks2 = k0 ^ k1 ^ 0x1BD11BDAu;
#define TF_ROT(x,n) (((x) << (n)) | ((x) >> (32 - (n))))
#define TF_RND(r) { x0 += x1; x1 = TF_ROT(x1, r); x1 ^= x0; }
    x0 += k0; x1 += k1;
    TF_RND(13) TF_RND(15) TF_RND(26) TF_RND(6)
    x0 += k1; x1 += ks2 + 1u;
    TF_RND(17) TF_RND(29) TF_RND(16) TF_RND(24)
    x0 += ks2; x1 += k0 + 2u;
    TF_RND(13) TF_RND(15) TF_RND(26) TF_RND(6)
    x0 += k0; x1 += k1 + 3u;
    TF_RND(17) TF_RND(29) TF_RND(16) TF_RND(24)
    x0 += k1; x1 += ks2 + 4u;
    TF_RND(13) TF_RND(15) TF_RND(26) TF_RND(6)
    x0 += ks2; x1 += k0 + 5u;
    o0 = x0; o1 = x1;
#undef TF_RND
#undef TF_ROT
}

// ---------- constants ----------
#define BATCH 32
#define TSAMP 524288
#define FRAMES 1024
#define HID 256
#define GATES 1024            // 4*HID
#define MROWS 32768           // BATCH*FRAMES
#define NCLS 29
#define NMASK 16777216u       // 32*1024*512
#define TCH 256               // time chunk
#define NCHUNK 4

// ---------- stats: per-batch mean / 1/(std+eps) ----------
__global__ __launch_bounds__(256) void k_stats1(const float* __restrict__ sig,
                                                float* __restrict__ psum,
                                                float* __restrict__ psq) {
    int blk = blockIdx.x;               // 1024 blocks, 32 per batch
    int tid = threadIdx.x;
    size_t base = (size_t)blk * 16384;
    float s = 0.f, q = 0.f;
    for (int i = 0; i < 16; ++i) {
        float4 v = *reinterpret_cast<const float4*>(sig + base + ((size_t)i * 256 + tid) * 4);
        s += v.x + v.y + v.z + v.w;
        q += v.x * v.x + v.y * v.y + v.z * v.z + v.w * v.w;
    }
    __shared__ float ls[4], lq[4];
    int w = tid >> 6, lane = tid & 63;
    for (int m = 32; m; m >>= 1) { s += __shfl_down(s, m); q += __shfl_down(q, m); }
    if (lane == 0) { ls[w] = s; lq[w] = q; }
    __syncthreads();
    if (tid == 0) {
        psum[blk] = ls[0] + ls[1] + ls[2] + ls[3];
        psq[blk]  = lq[0] + lq[1] + lq[2] + lq[3];
    }
}

__global__ __launch_bounds__(1024) void k_stats2(const float* __restrict__ psum,
                                                 const float* __restrict__ psq,
                                                 float* __restrict__ mu,
                                                 float* __restrict__ rstd) {
    int tid = threadIdx.x;              // 1024 = 32 batches * 32 chunks
    float s = psum[tid], q = psq[tid];
    for (int m = 16; m; m >>= 1) { s += __shfl_down(s, m); q += __shfl_down(q, m); }
    if ((tid & 31) == 0) {
        int b = tid >> 5;
        float m_ = s * (1.f / (float)TSAMP);
        float v  = q * (1.f / (float)TSAMP) - m_ * m_;
        float sd = sqrtf(fmaxf(v, 0.f));
        mu[b] = m_;
        rstd[b] = 1.f / (sd + 1e-8f);
    }
}

// ---------- normalize + frame -> bf16 hi/lo pair [32768][512] ----------
__global__ __launch_bounds__(256) void k_norm(const float* __restrict__ sig,
                                              const float* __restrict__ mu,
                                              const float* __restrict__ rstd,
                                              unsigned short* __restrict__ xh,
                                              unsigned short* __restrict__ xl) {
    size_t gid = (size_t)blockIdx.x * 256 + threadIdx.x;   // 4194304 threads, 4 elems each
    int b = (int)(gid >> 17);
    float m = mu[b], r = rstd[b];
    float4 v = *reinterpret_cast<const float4*>(sig + gid * 4);
    float f0 = (v.x - m) * r, f1 = (v.y - m) * r, f2 = (v.z - m) * r, f3 = (v.w - m) * r;
    ushort4 oh, ol;
    oh.x = f2bf(f0); ol.x = f2bf(f0 - b2f(oh.x));
    oh.y = f2bf(f1); ol.y = f2bf(f1 - b2f(oh.y));
    oh.z = f2bf(f2); ol.z = f2bf(f2 - b2f(oh.z));
    oh.w = f2bf(f3); ol.w = f2bf(f3 - b2f(oh.w));
    *reinterpret_cast<ushort4*>(xh + gid * 4) = oh;
    *reinterpret_cast<ushort4*>(xl + gid * 4) = ol;
}

// ---------- weight prep: transpose + hi/lo split ----------
// WT[ld][n][k] = bf16pair(Wih[ld][k][n]);  ld in [0,6), n in [0,1024), k in [0,512)
__global__ __launch_bounds__(256) void k_wih_t(const float* __restrict__ Wih,
                                               unsigned short* __restrict__ WTh,
                                               unsigned short* __restrict__ WTl) {
    size_t gid = (size_t)blockIdx.x * 256 + threadIdx.x;   // 3145728
    int k = (int)(gid & 511);
    int n = (int)((gid >> 9) & 1023);
    int ld = (int)(gid >> 19);
    float w = Wih[((size_t)ld * 512 + k) * 1024 + n];
    unsigned short h = f2bf(w);
    WTh[gid] = h;
    WTl[gid] = f2bf(w - b2f(h));
}

// ---------- chunked input GEMM ----------
// C[8192][1024] = A_rows x WTdir^T where chunk-local row r maps to
// global x row m = (r>>8)*1024 + t0 + (r&255).
// split-bf16: acc = Ah*Bh + Al*Bh + Ah*Bl (fp32-class precision).
__global__ __launch_bounds__(256) void k_gemm_chunk(const unsigned short* __restrict__ Ah,
                                                    const unsigned short* __restrict__ Al,
                                                    const unsigned short* __restrict__ BTh,
                                                    const unsigned short* __restrict__ BTl,
                                                    float* __restrict__ C,
                                                    int t0) {
    __shared__ __align__(16) unsigned short Ahs[128][40];
    __shared__ __align__(16) unsigned short Als[128][40];
    __shared__ __align__(16) unsigned short Bhs[128][40];
    __shared__ __align__(16) unsigned short Bls[128][40];
    const int tid = threadIdx.x;
    const int tm = blockIdx.y * 128;     // gridDim.y = 64  (8192 chunk rows)
    const int tn = blockIdx.x * 128;     // gridDim.x = 8   (1024 gate cols)
    const int lane = tid & 63, w = tid >> 6;
    const int wr = w >> 1, wc = w & 1;
    const int l15 = lane & 15, lk = (lane >> 4) * 8;
    f32x4 acc[4][4];
    for (int i = 0; i < 4; ++i)
        for (int j = 0; j < 4; ++j)
            acc[i][j] = (f32x4){0.f, 0.f, 0.f, 0.f};
    const int srow = tid >> 1, scol = (tid & 1) * 16;
    const int rg = tm + srow;
    const size_t am = (size_t)((rg >> 8) * 1024 + t0 + (rg & 255)) * 512;
    const size_t bm = (size_t)(tn + srow) * 512;
    for (int kt = 0; kt < 512; kt += 32) {
        *reinterpret_cast<uint4*>(&Ahs[srow][scol])     = *reinterpret_cast<const uint4*>(&Ah[am + kt + scol]);
        *reinterpret_cast<uint4*>(&Ahs[srow][scol + 8]) = *reinterpret_cast<const uint4*>(&Ah[am + kt + scol + 8]);
        *reinterpret_cast<uint4*>(&Als[srow][scol])     = *reinterpret_cast<const uint4*>(&Al[am + kt + scol]);
        *reinterpret_cast<uint4*>(&Als[srow][scol + 8]) = *reinterpret_cast<const uint4*>(&Al[am + kt + scol + 8]);
        *reinterpret_cast<uint4*>(&Bhs[srow][scol])     = *reinterpret_cast<const uint4*>(&BTh[bm + kt + scol]);
        *reinterpret_cast<uint4*>(&Bhs[srow][scol + 8]) = *reinterpret_cast<const uint4*>(&BTh[bm + kt + scol + 8]);
        *reinterpret_cast<uint4*>(&Bls[srow][scol])     = *reinterpret_cast<const uint4*>(&BTl[bm + kt + scol]);
        *reinterpret_cast<uint4*>(&Bls[srow][scol + 8]) = *reinterpret_cast<const uint4*>(&BTl[bm + kt + scol + 8]);
        __syncthreads();
        bf16x8 afh[4], afl[4], bfh[4], bfl[4];
        for (int m = 0; m < 4; ++m) {
            afh[m] = *reinterpret_cast<const bf16x8*>(&Ahs[wr * 64 + m * 16 + l15][lk]);
            afl[m] = *reinterpret_cast<const bf16x8*>(&Als[wr * 64 + m * 16 + l15][lk]);
        }
        for (int n = 0; n < 4; ++n) {
            bfh[n] = *reinterpret_cast<const bf16x8*>(&Bhs[wc * 64 + n * 16 + l15][lk]);
            bfl[n] = *reinterpret_cast<const bf16x8*>(&Bls[wc * 64 + n * 16 + l15][lk]);
        }
        for (int m = 0; m < 4; ++m)
            for (int n = 0; n < 4; ++n) {
                acc[m][n] = __builtin_amdgcn_mfma_f32_16x16x32_bf16(afh[m], bfh[n], acc[m][n], 0, 0, 0);
                acc[m][n] = __builtin_amdgcn_mfma_f32_16x16x32_bf16(afl[m], bfh[n], acc[m][n], 0, 0, 0);
                acc[m][n] = __builtin_amdgcn_mfma_f32_16x16x32_bf16(afh[m], bfl[n], acc[m][n], 0, 0, 0);
            }
        __syncthreads();
    }
    const int rbase = tm + wr * 64 + (lane >> 4) * 4;
    const int cbase = tn + wc * 64 + l15;
    for (int m = 0; m < 4; ++m)
        for (int n = 0; n < 4; ++n)
            for (int r = 0; r < 4; ++r) {
                int row = rbase + m * 16 + r;
                int col = cbase + n * 16;
                C[(size_t)row * 1024 + col] = acc[m][n][r];
            }
}

// ---------- LSTM scan chunk (fp32): one block per (dir,batch); 512 threads ----------
// Processes TCH steps; h/c state carried in global hstate/cstate between chunks.
__global__ __launch_bounds__(512) void k_scan_chunk(const float* __restrict__ Whh,
                                                    const float* __restrict__ bias,
                                                    const float* __restrict__ xgA,  // fwd  [32*256][1024]
                                                    const float* __restrict__ xgB,  // bwd  [32*256][1024]
                                                    float* __restrict__ hout,
                                                    float* __restrict__ hstate,
                                                    float* __restrict__ cstate,
                                                    int layer, int chunk) {
    const int d = blockIdx.x >> 5;
    const int b = blockIdx.x & 31;
    const int tid = threadIdx.x;        // 0..511
    const int j = tid & 255, kh = tid >> 8;
    const float* W = Whh + (size_t)(layer * 2 + d) * HID * GATES + (size_t)kh * 128 * GATES;
    const float* bs = bias + (size_t)(layer * 2 + d) * GATES;
    __shared__ __align__(16) float hcur[HID];
    __shared__ float gpart[2][GATES];
    __shared__ float blds[GATES];
    for (int i = tid; i < GATES; i += 512) blds[i] = bs[i];
    float c = 0.f;
    if (tid < HID) {
        if (chunk == 0) {
            hcur[tid] = 0.f;
        } else {
            hcur[tid] = hstate[(size_t)blockIdx.x * HID + tid];
            c = cstate[(size_t)blockIdx.x * HID + tid];
        }
    }
    __syncthreads();
    const int col0 = j * 4;
    const float* hbase = hcur + kh * 128;
    const float* xbase = (d ? xgB : xgA) + (size_t)b * TCH * 1024;
    for (int sl = 0; sl < TCH; ++sl) {
        const int tloc = d ? (TCH - 1 - sl) : sl;           // row within chunk buffer
        const int tg = d ? (FRAMES - 1 - (chunk * TCH + sl))
                         : (chunk * TCH + sl);              // global frame index
        float a0 = 0.f, a1 = 0.f, a2 = 0.f, a3 = 0.f;
        const float* wp = W + col0;
        #pragma unroll 4
        for (int k4 = 0; k4 < 32; ++k4) {
            float4 hk = *reinterpret_cast<const float4*>(hbase + k4 * 4);
            float4 w0 = *reinterpret_cast<const float4*>(wp);
            float4 w1 = *reinterpret_cast<const float4*>(wp + 1024);
            float4 w2 = *reinterpret_cast<const float4*>(wp + 2048);
            float4 w3 = *reinterpret_cast<const float4*>(wp + 3072);
            wp += 4096;
            a0 += hk.x * w0.x + hk.y * w1.x + hk.z * w2.x + hk.w * w3.x;
            a1 += hk.x * w0.y + hk.y * w1.y + hk.z * w2.y + hk.w * w3.y;
            a2 += hk.x * w0.z + hk.y * w1.z + hk.z * w2.z + hk.w * w3.z;
            a3 += hk.x * w0.w + hk.y * w1.w + hk.z * w2.w + hk.w * w3.w;
        }
        gpart[kh][col0]     = a0;
        gpart[kh][col0 + 1] = a1;
        gpart[kh][col0 + 2] = a2;
        gpart[kh][col0 + 3] = a3;
        __syncthreads();
        if (tid < HID) {
            const float* xr = xbase + (size_t)tloc * 1024;
            float gi = gpart[0][tid]       + gpart[1][tid]       + blds[tid]       + xr[tid];
            float gf = gpart[0][256 + tid] + gpart[1][256 + tid] + blds[256 + tid] + xr[256 + tid];
            float gg = gpart[0][512 + tid] + gpart[1][512 + tid] + blds[512 + tid] + xr[512 + tid];
            float go = gpart[0][768 + tid] + gpart[1][768 + tid] + blds[768 + tid] + xr[768 + tid];
            float si = 1.f / (1.f + expf(-gi));
            float sf = 1.f / (1.f + expf(-gf));
            float so = 1.f / (1.f + expf(-go));
            c = sf * c + si * tanhf(gg);
            float h = so * tanhf(c);
            hout[((size_t)(d * BATCH + b) * FRAMES + tg) * HID + tid] = h;
            hcur[tid] = h;
        }
        __syncthreads();
    }
    if (tid < HID) {
        hstate[(size_t)blockIdx.x * HID + tid] = hcur[tid];
        cstate[(size_t)blockIdx.x * HID + tid] = c;
    }
}

// ---------- dropout(0.5) + ReLU + concat, JAX PARTITIONABLE threefry ----------
// JAX >= 0.4.36 default: bits[i] = o0 ^ o1 where (o0,o1) = threefry2x32(key, hi32(i)=0, lo32(i)=i);
// keep = (bits >> 9 | 0x3f800000 as float) - 1 < 0.5  <=>  MSB(bits) == 0.
// One thread per element i of x [32,1024,512].
// layers 0,1: write bf16 hi/lo pair; layer 2: write fp32 only.
__global__ __launch_bounds__(256) void k_dropout(const float* __restrict__ h,
                                                 unsigned short* __restrict__ xh,  // may be null
                                                 unsigned short* __restrict__ xl,  // may be null
                                                 float* __restrict__ xf,           // may be null
                                                 uint32_t fk0, uint32_t fk1) {
    uint32_t i = blockIdx.x * 256u + threadIdx.x;    // grid 65536 -> NMASK threads
    uint32_t o0, o1;
    tf2x32(fk0, fk1, 0u, i, o0, o1);
    uint32_t bits = o0 ^ o1;
    uint32_t f = i & 511u;
    uint32_t t = (i >> 9) & 1023u;
    uint32_t b = i >> 19;                            // 0..31
    uint32_t dv = f >> 8, n = f & 255u;
    float v = h[(((size_t)dv * BATCH + b) * FRAMES + t) * HID + n];
    float o = (((bits >> 31) == 0u) && v > 0.f) ? 2.f * v : 0.f;
    if (xh != nullptr) {
        unsigned short hb_ = f2bf(o);
        xh[i] = hb_;
        xl[i] = f2bf(o - b2f(hb_));
    }
    if (xf != nullptr) xf[i] = o;
}

// ---------- output projection: out[32768][29] = Xf[32768][512] @ Wout + bout ----------
__global__ __launch_bounds__(256) void k_out(const float* __restrict__ xf,
                                             const float* __restrict__ Wout,
                                             const float* __restrict__ bout,
                                             float* __restrict__ out) {
    __shared__ __align__(16) float Xs[64][68];
    const int tid = threadIdx.x;
    const int r = tid & 63, cg = tid >> 6;           // 4 col-groups of 8 (last has 5)
    const int row0 = blockIdx.x * 64;
    float acc[8] = {0.f, 0.f, 0.f, 0.f, 0.f, 0.f, 0.f, 0.f};
    for (int kc = 0; kc < 512; kc += 64) {
        int sr = tid >> 2, sc = (tid & 3) * 16;
        const float* src = xf + (size_t)(row0 + sr) * 512 + kc + sc;
        *reinterpret_cast<float4*>(&Xs[sr][sc])      = *reinterpret_cast<const float4*>(src);
        *reinterpret_cast<float4*>(&Xs[sr][sc + 4])  = *reinterpret_cast<const float4*>(src + 4);
        *reinterpret_cast<float4*>(&Xs[sr][sc + 8])  = *reinterpret_cast<const float4*>(src + 8);
        *reinterpret_cast<float4*>(&Xs[sr][sc + 12]) = *reinterpret_cast<const float4*>(src + 12);
        __syncthreads();
        for (int k = 0; k < 64; ++k) {
            float xv = Xs[r][k];
            const float* wr = Wout + (size_t)(kc + k) * NCLS + cg * 8;
            #pragma unroll
            for (int cc = 0; cc < 8; ++cc)
                if (cg * 8 + cc < NCLS) acc[cc] = fmaf(xv, wr[cc], acc[cc]);
        }
        __syncthreads();
    }
    for (int cc = 0; cc < 8; ++cc) {
        int col = cg * 8 + cc;
        if (col < NCLS) out[(size_t)(row0 + r) * NCLS + col] = acc[cc] + bout[col];
    }
}

// ---------- launch ----------
extern "C" void kernel_launch(void* const* d_in, const int* in_sizes, int n_in,
                              void* d_out, int out_size, void* d_ws, size_t ws_size,
                              hipStream_t stream) {
    const float* sig  = (const float*)d_in[0];
    const float* Wih  = (const float*)d_in[1];
    const float* Whh  = (const float*)d_in[2];
    const float* bias = (const float*)d_in[3];
    const float* Wout = (const float*)d_in[4];
    const float* bout = (const float*)d_in[5];
    float* out = (float*)d_out;

    char* ws = (char*)d_ws;
    size_t off = 0;
    auto alloc = [&](size_t bytes) -> void* {
        void* p = ws + off;
        off += (bytes + 255) & ~(size_t)255;
        return p;
    };
    float* psum           = (float*)alloc(1024 * 4);
    float* psq            = (float*)alloc(1024 * 4);
    float* mu             = (float*)alloc(32 * 4);
    float* rstd           = (float*)alloc(32 * 4);
    unsigned short* WThi  = (unsigned short*)alloc((size_t)6 * 1024 * 512 * 2);     // 6.3 MB
    unsigned short* WTlo  = (unsigned short*)alloc((size_t)6 * 1024 * 512 * 2);     // 6.3 MB
    unsigned short* xhi   = (unsigned short*)alloc((size_t)MROWS * 512 * 2);        // 33.5 MB
    unsigned short* xlo   = (unsigned short*)alloc((size_t)MROWS * 512 * 2);        // 33.5 MB (adjacent to xhi)
    float* xgA            = (float*)alloc((size_t)BATCH * TCH * 1024 * 4);          // 33.5 MB
    float* xgB            = (float*)alloc((size_t)BATCH * TCH * 1024 * 4);          // 33.5 MB
    float* hb             = (float*)alloc((size_t)2 * BATCH * FRAMES * HID * 4);    // 67 MB
    float* hstate         = (float*)alloc((size_t)64 * HID * 4);
    float* cstate         = (float*)alloc((size_t)64 * HID * 4);
    // Total ~214 MB (round-3 layout, proven to run without faults).
    // Layer-2 fp32 activations overlay the (then-dead) xhi+xlo region (67 MB).
    float* xf32           = (float*)xhi;

    k_stats1<<<1024, 256, 0, stream>>>(sig, psum, psq);
    k_stats2<<<1, 1024, 0, stream>>>(psum, psq, mu, rstd);
    k_norm<<<16384, 256, 0, stream>>>(sig, mu, rstd, xhi, xlo);
    k_wih_t<<<12288, 256, 0, stream>>>(Wih, WThi, WTlo);

    for (int l = 0; l < 3; ++l) {
        const unsigned short* Bh0 = WThi + (size_t)(l * 2 + 0) * 1024 * 512;
        const unsigned short* Bl0 = WTlo + (size_t)(l * 2 + 0) * 1024 * 512;
        const unsigned short* Bh1 = WThi + (size_t)(l * 2 + 1) * 1024 * 512;
        const unsigned short* Bl1 = WTlo + (size_t)(l * 2 + 1) * 1024 * 512;
        for (int c = 0; c < NCHUNK; ++c) {
            dim3 gg(8, 64);
            int t0f = c * TCH;                       // fwd chunk frames
            int t0b = (NCHUNK - 1 - c) * TCH;        // bwd chunk frames
            k_gemm_chunk<<<gg, 256, 0, stream>>>(xhi, xlo, Bh0, Bl0, xgA, t0f);
            k_gemm_chunk<<<gg, 256, 0, stream>>>(xhi, xlo, Bh1, Bl1, xgB, t0b);
            k_scan_chunk<<<64, 512, 0, stream>>>(Whh, bias, xgA, xgB, hb, hstate, cstate, l, c);
        }
        uint32_t fk0, fk1;
        tf2x32(0u, 42u, 0u, (uint32_t)l, fk0, fk1);
        if (l < 2)
            k_dropout<<<65536, 256, 0, stream>>>(hb, xhi, xlo, nullptr, fk0, fk1);
        else
            k_dropout<<<65536, 256, 0, stream>>>(hb, nullptr, nullptr, xf32, fk0, fk1);
    }
    k_out<<<512, 256, 0, stream>>>(xf32, Wout, bout, out);
}